// Round 19
// baseline (474.357 us; speedup 1.0000x reference)
//
#include <hip/hip_runtime.h>

#define N_USERS 100000
#define N_ITEMS 50000
#define N_NODES 150000
#define EMBED_DIM 64
#define N_EDGES 4800000
#define N_LAYERS 3

// two-level row radix: coarse buckets of 512 rows
#define CB_SHIFT 9
#define CB_ROWS (1 << CB_SHIFT)                          // 512
#define NC ((N_NODES + CB_ROWS - 1) >> CB_SHIFT)         // 293

#define EPB 8192                                         // edges per block (hist/part)
#define NPB ((N_EDGES + EPB - 1) / EPB)                  // 586
#define INIT_BLOCKS ((N_NODES * EMBED_DIM / 4 + 255) / 256)   // 9375

// ---------- bf16 helpers (RNE) ----------
__device__ __forceinline__ unsigned short f2bf(float f) {
    unsigned u = __float_as_uint(f);
    u += 0x7fffu + ((u >> 16) & 1u);
    return (unsigned short)(u >> 16);
}
__device__ __forceinline__ float bf2f(unsigned short h) {
    return __uint_as_float((unsigned)h << 16);
}

// ---------- packed edge: (col << 14) | val_e4m10 ----------
__device__ __forceinline__ unsigned enc_val14(unsigned vbits) {
    unsigned r = vbits + 0x1000u;              // round at dropped-bits midpoint
    unsigned exp = (r >> 23) & 0xffu;
    if (exp < 112u) return 0u;                 // decodes as 2^-15 (<=3e-5 err)
    return ((exp - 112u) << 10) | ((r >> 13) & 0x3ffu);
}
// 3-op decode: (p<<18) kills col bits; >>5 lands exp4 at [23:26], m10 at [13:22].
__device__ __forceinline__ float dec_val14(unsigned p) {
    return __uint_as_float(((p << 18) >> 5) + 0x38000000u);
}

// ---------------- fused: per-block coarse histogram + init cur0=bf16(emb) ----
__global__ __launch_bounds__(256)
void k_hist_init(const int* __restrict__ row, int* __restrict__ blk_hist,
                 const float* __restrict__ user_emb,
                 const float* __restrict__ item_emb,
                 unsigned short* __restrict__ curb) {
    __shared__ int h[NC];
    int blk = blockIdx.x;
    if (blk < NPB) {
        for (int i = threadIdx.x; i < NC; i += 256) h[i] = 0;
        __syncthreads();
        int e0 = blk * EPB;
        int e1 = e0 + EPB; if (e1 > N_EDGES) e1 = N_EDGES;
        for (int e = e0 + threadIdx.x; e < e1; e += 256)
            atomicAdd(&h[row[e] >> CB_SHIFT], 1);
        __syncthreads();
        for (int i = threadIdx.x; i < NC; i += 256)
            blk_hist[blk * NC + i] = h[i];
    } else {
        int i = (blk - NPB) * 256 + threadIdx.x;
        const int total = N_NODES * EMBED_DIM / 4;
        if (i >= total) return;
        const int user_elems = N_USERS * EMBED_DIM / 4;
        float4 v;
        if (i < user_elems) v = ((const float4*)user_emb)[i];
        else                v = ((const float4*)item_emb)[i - user_elems];
        ushort4 o;
        o.x = f2bf(v.x); o.y = f2bf(v.y); o.z = f2bf(v.z); o.w = f2bf(v.w);
        ((ushort4*)curb)[i] = o;
    }
}

// ---------------- 2D scan: bucket bases + exact per-(block,bucket) offsets ----
__global__ __launch_bounds__(512)
void k_scan2d(const int* __restrict__ bh,
              int* __restrict__ cbase,
              int* __restrict__ boff) {
    __shared__ int part[512];
    int t = threadIdx.x;
    int total = 0;
    if (t < NC)
        for (int blk = 0; blk < NPB; ++blk) total += bh[blk * NC + t];
    part[t] = total;
    __syncthreads();
    for (int o = 1; o < 512; o <<= 1) {
        int v = (t >= o) ? part[t - o] : 0;
        __syncthreads();
        part[t] += v;
        __syncthreads();
    }
    int base = t ? part[t - 1] : 0;     // exclusive
    if (t < NC) {
        cbase[t] = base;
        int run = base;
        for (int blk = 0; blk < NPB; ++blk) {
            boff[blk * NC + t] = run;
            run += bh[blk * NC + t];
        }
    }
    if (t == 0) cbase[NC] = N_EDGES;
}

// ---------------- single-pass partition with precomputed offsets ----------
// writes final-format cvp=(col<<14)|val14 (4B) + rl16 (2B) — 6B/edge payload.
__global__ __launch_bounds__(512)
void k_part_f(const int* __restrict__ row,
              const int* __restrict__ col,
              const int* __restrict__ valI,
              const int* __restrict__ boff,
              unsigned* __restrict__ cvp,
              unsigned short* __restrict__ rl16) {
    __shared__ int off[NC];
    int blk = blockIdx.x;
    int e0 = blk * EPB;
    int e1 = e0 + EPB; if (e1 > N_EDGES) e1 = N_EDGES;
    for (int i = threadIdx.x; i < NC; i += 512)
        off[i] = boff[blk * NC + i];
    __syncthreads();
    for (int e = e0 + threadIdx.x; e < e1; e += 512) {
        int r = row[e];
        int cb = r >> CB_SHIFT;
        int p = atomicAdd(&off[cb], 1);
        cvp[p]  = ((unsigned)col[e] << 14) | enc_val14((unsigned)valI[e]);
        rl16[p] = (unsigned short)(r & (CB_ROWS - 1));
    }
}

// ---------------- fine counting sort -> packed 4B CSR + rowptr ------------
__global__ __launch_bounds__(512)
void k_sort_c(const int* __restrict__ cbase,
              const unsigned* __restrict__ cvp,
              const unsigned short* __restrict__ rl16,
              unsigned* __restrict__ csr,
              int* __restrict__ rowptr) {
    __shared__ int h[CB_ROWS];
    __shared__ int off[CB_ROWS];
    int b = blockIdx.x;
    int seg0 = cbase[b], seg1 = cbase[b + 1];
    h[threadIdx.x] = 0;
    __syncthreads();
    for (int e = seg0 + threadIdx.x; e < seg1; e += 512)
        atomicAdd(&h[rl16[e]], 1);
    __syncthreads();
    for (int o = 1; o < CB_ROWS; o <<= 1) {
        int t = (threadIdx.x >= o) ? h[threadIdx.x - o] : 0;
        __syncthreads();
        h[threadIdx.x] += t;
        __syncthreads();
    }
    int row0 = b << CB_SHIFT;
    int nrows = N_NODES - row0; if (nrows > CB_ROWS) nrows = CB_ROWS;
    int excl = threadIdx.x ? h[threadIdx.x - 1] : 0;
    off[threadIdx.x] = excl;
    if (threadIdx.x < nrows) rowptr[row0 + threadIdx.x] = seg0 + excl;
    __syncthreads();
    for (int e = seg0 + threadIdx.x; e < seg1; e += 512) {
        int rl = rl16[e];
        int p = atomicAdd(&off[rl], 1);
        csr[seg0 + p] = cvp[e];
    }
    if (b == NC - 1 && threadIdx.x == 0) rowptr[N_NODES] = N_EDGES;
}

// ---------------- gather core: 16-deep MLP dot over one row ----------------
__device__ __forceinline__ float spmv_row(const unsigned* __restrict__ cv,
                                          const unsigned short* __restrict__ x,
                                          int start, int end, int lane) {
    float a0 = 0.f, a1 = 0.f, a2 = 0.f, a3 = 0.f;
    float a4 = 0.f, a5 = 0.f, a6 = 0.f, a7 = 0.f;
    int j = start;
    for (; j + 16 <= end; j += 16) {
        unsigned p0 = cv[j + 0],  p1 = cv[j + 1],  p2 = cv[j + 2],  p3 = cv[j + 3];
        unsigned p4 = cv[j + 4],  p5 = cv[j + 5],  p6 = cv[j + 6],  p7 = cv[j + 7];
        unsigned p8 = cv[j + 8],  p9 = cv[j + 9],  pa = cv[j + 10], pb = cv[j + 11];
        unsigned pc = cv[j + 12], pd = cv[j + 13], pe = cv[j + 14], pf = cv[j + 15];
        float x0 = bf2f(x[((size_t)(p0 >> 14) << 6) + lane]);
        float x1 = bf2f(x[((size_t)(p1 >> 14) << 6) + lane]);
        float x2 = bf2f(x[((size_t)(p2 >> 14) << 6) + lane]);
        float x3 = bf2f(x[((size_t)(p3 >> 14) << 6) + lane]);
        float x4 = bf2f(x[((size_t)(p4 >> 14) << 6) + lane]);
        float x5 = bf2f(x[((size_t)(p5 >> 14) << 6) + lane]);
        float x6 = bf2f(x[((size_t)(p6 >> 14) << 6) + lane]);
        float x7 = bf2f(x[((size_t)(p7 >> 14) << 6) + lane]);
        float x8 = bf2f(x[((size_t)(p8 >> 14) << 6) + lane]);
        float x9 = bf2f(x[((size_t)(p9 >> 14) << 6) + lane]);
        float xa = bf2f(x[((size_t)(pa >> 14) << 6) + lane]);
        float xb = bf2f(x[((size_t)(pb >> 14) << 6) + lane]);
        float xc = bf2f(x[((size_t)(pc >> 14) << 6) + lane]);
        float xd = bf2f(x[((size_t)(pd >> 14) << 6) + lane]);
        float xe = bf2f(x[((size_t)(pe >> 14) << 6) + lane]);
        float xf = bf2f(x[((size_t)(pf >> 14) << 6) + lane]);
        a0 += dec_val14(p0) * x0;  a1 += dec_val14(p1) * x1;
        a2 += dec_val14(p2) * x2;  a3 += dec_val14(p3) * x3;
        a4 += dec_val14(p4) * x4;  a5 += dec_val14(p5) * x5;
        a6 += dec_val14(p6) * x6;  a7 += dec_val14(p7) * x7;
        a0 += dec_val14(p8) * x8;  a1 += dec_val14(p9) * x9;
        a2 += dec_val14(pa) * xa;  a3 += dec_val14(pb) * xb;
        a4 += dec_val14(pc) * xc;  a5 += dec_val14(pd) * xd;
        a6 += dec_val14(pe) * xe;  a7 += dec_val14(pf) * xf;
    }
    if (j + 8 <= end) {
        unsigned p0 = cv[j + 0], p1 = cv[j + 1], p2 = cv[j + 2], p3 = cv[j + 3];
        unsigned p4 = cv[j + 4], p5 = cv[j + 5], p6 = cv[j + 6], p7 = cv[j + 7];
        a0 += dec_val14(p0) * bf2f(x[((size_t)(p0 >> 14) << 6) + lane]);
        a1 += dec_val14(p1) * bf2f(x[((size_t)(p1 >> 14) << 6) + lane]);
        a2 += dec_val14(p2) * bf2f(x[((size_t)(p2 >> 14) << 6) + lane]);
        a3 += dec_val14(p3) * bf2f(x[((size_t)(p3 >> 14) << 6) + lane]);
        a4 += dec_val14(p4) * bf2f(x[((size_t)(p4 >> 14) << 6) + lane]);
        a5 += dec_val14(p5) * bf2f(x[((size_t)(p5 >> 14) << 6) + lane]);
        a6 += dec_val14(p6) * bf2f(x[((size_t)(p6 >> 14) << 6) + lane]);
        a7 += dec_val14(p7) * bf2f(x[((size_t)(p7 >> 14) << 6) + lane]);
        j += 8;
    }
    if (j + 4 <= end) {
        unsigned p0 = cv[j + 0], p1 = cv[j + 1], p2 = cv[j + 2], p3 = cv[j + 3];
        a0 += dec_val14(p0) * bf2f(x[((size_t)(p0 >> 14) << 6) + lane]);
        a1 += dec_val14(p1) * bf2f(x[((size_t)(p1 >> 14) << 6) + lane]);
        a2 += dec_val14(p2) * bf2f(x[((size_t)(p2 >> 14) << 6) + lane]);
        a3 += dec_val14(p3) * bf2f(x[((size_t)(p3 >> 14) << 6) + lane]);
        j += 4;
    }
    for (; j < end; ++j) {
        unsigned p = cv[j];
        a0 += dec_val14(p) * bf2f(x[((size_t)(p >> 14) << 6) + lane]);
    }
    return ((a0 + a1) + (a2 + a3)) + ((a4 + a5) + (a6 + a7));
}

// ---------------- layers 1..L-1: gather SpMV, write bf16 nxt only ----------------
__global__ __launch_bounds__(256)
void lgcn_spmv_mid(const int* __restrict__ rowptr,
                   const unsigned* __restrict__ cv,
                   const unsigned short* __restrict__ x,
                   unsigned short* __restrict__ nxt) {
    int t = blockIdx.x * blockDim.x + threadIdx.x;
    int wave = t >> 6;
    int lane = t & 63;
    if (wave >= N_NODES) return;
    int r = __builtin_amdgcn_readfirstlane(wave);
    float sum = spmv_row(cv, x, rowptr[r], rowptr[r + 1], lane);
    nxt[((size_t)r << 6) + lane] = f2bf(sum);
}

// ---------------- last layer: gather + fused final combine ----------------
__global__ __launch_bounds__(256)
void lgcn_spmv_last(const int* __restrict__ rowptr,
                    const unsigned* __restrict__ cv,
                    const unsigned short* __restrict__ x,     // e2 (bf16)
                    const unsigned short* __restrict__ e1,    // layer-1 out (bf16)
                    const float* __restrict__ user_emb,
                    const float* __restrict__ item_emb,
                    float* __restrict__ out) {
    int t = blockIdx.x * blockDim.x + threadIdx.x;
    int wave = t >> 6;
    int lane = t & 63;
    if (wave >= N_NODES) return;
    int r = __builtin_amdgcn_readfirstlane(wave);
    float sum = spmv_row(cv, x, rowptr[r], rowptr[r + 1], lane);
    size_t o = ((size_t)r << 6) + lane;
    float e0 = (r < N_USERS) ? user_emb[o]
                             : item_emb[o - ((size_t)N_USERS << 6)];
    float v = ((e0 + bf2f(e1[o])) + bf2f(x[o])) + sum;
    out[o] = v * 0.25f;
}

// ---------------- fallback (atomic scatter, f32) ----------------
__global__ void lgcn_init(const float* __restrict__ user_emb,
                          const float* __restrict__ item_emb,
                          float* __restrict__ cur,
                          float* __restrict__ acc) {
    int i = blockIdx.x * blockDim.x + threadIdx.x;
    const int total = N_NODES * EMBED_DIM / 4;
    if (i >= total) return;
    const int user_elems = N_USERS * EMBED_DIM / 4;
    float4 v;
    if (i < user_elems) v = ((const float4*)user_emb)[i];
    else                v = ((const float4*)item_emb)[i - user_elems];
    ((float4*)cur)[i] = v;
    ((float4*)acc)[i] = v;
}

__global__ void lgcn_spmm_atomic(const int* __restrict__ row,
                                 const int* __restrict__ col,
                                 const float* __restrict__ val,
                                 const float* __restrict__ x,
                                 float* __restrict__ y) {
    long long t = (long long)blockIdx.x * blockDim.x + threadIdx.x;
    int e = (int)(t >> 6);
    int d = (int)(t & 63);
    if (e >= N_EDGES) return;
    atomicAdd(&y[(long long)row[e] * EMBED_DIM + d],
              val[e] * x[(long long)col[e] * EMBED_DIM + d]);
}

__global__ void lgcn_accum(const float* __restrict__ cur,
                           float* __restrict__ acc, float s) {
    int i = blockIdx.x * blockDim.x + threadIdx.x;
    const int total = N_NODES * EMBED_DIM / 4;
    if (i >= total) return;
    float4 a = ((const float4*)acc)[i];
    float4 c = ((const float4*)cur)[i];
    a.x = (a.x + c.x) * s; a.y = (a.y + c.y) * s;
    a.z = (a.z + c.z) * s; a.w = (a.w + c.w) * s;
    ((float4*)acc)[i] = a;
}

extern "C" void kernel_launch(void* const* d_in, const int* in_sizes, int n_in,
                              void* d_out, int out_size, void* d_ws, size_t ws_size,
                              hipStream_t stream) {
    const int*   adj_row  = (const int*)d_in[0];
    const int*   adj_col  = (const int*)d_in[1];
    const float* adj_val  = (const float*)d_in[2];
    const int*   adj_valI = (const int*)d_in[2];
    const float* user_emb = (const float*)d_in[3];
    const float* item_emb = (const float*)d_in[4];
    float* out = (float*)d_out;

    const size_t buf_elems = (size_t)N_NODES * EMBED_DIM;

    // ---- workspace layout ----
    char* wp = (char*)d_ws;
    int* cbase  = (int*)wp;  wp += (size_t)(NC + 1) * sizeof(int);
    int* rowptr = (int*)wp;  wp += (size_t)(N_NODES + 1) * sizeof(int);
    wp = (char*)(((size_t)wp + 127) & ~(size_t)127);
    unsigned* cvp = (unsigned*)wp;        wp += (size_t)N_EDGES * sizeof(unsigned);
    wp = (char*)(((size_t)wp + 127) & ~(size_t)127);
    unsigned short* rl16 = (unsigned short*)wp; wp += (size_t)N_EDGES * sizeof(unsigned short);
    wp = (char*)(((size_t)wp + 127) & ~(size_t)127);
    unsigned* csr = (unsigned*)wp;        wp += (size_t)N_EDGES * sizeof(unsigned);
    wp = (char*)(((size_t)wp + 127) & ~(size_t)127);
    unsigned short* curb = (unsigned short*)wp; wp += buf_elems * sizeof(unsigned short);
    wp = (char*)(((size_t)wp + 127) & ~(size_t)127);
    unsigned short* nxtb = (unsigned short*)wp; wp += buf_elems * sizeof(unsigned short);
    size_t needed = (size_t)(wp - (char*)d_ws);
    // blk_hist/boff alias the csr region (dead until k_sort_c writes it);
    // e2 buffer aliases the cvp region (dead after k_sort_c; 19.2MB each).
    int* blk_hist = (int*)csr;                       // NPB*NC ints (~687 KB)
    int* boff     = blk_hist + (size_t)NPB * NC;     // NPB*NC ints
    unsigned short* e2b = (unsigned short*)cvp;

    if (needed <= ws_size) {
        // ---- build: fused per-block hist + init, 2D scan, offset-scatter, sort ----
        k_hist_init<<<NPB + INIT_BLOCKS, 256, 0, stream>>>(adj_row, blk_hist,
                                                           user_emb, item_emb, curb);
        k_scan2d<<<1, 512, 0, stream>>>(blk_hist, cbase, boff);
        k_part_f<<<NPB, 512, 0, stream>>>(adj_row, adj_col, adj_valI, boff, cvp, rl16);
        k_sort_c<<<NC, 512, 0, stream>>>(cbase, cvp, rl16, csr, rowptr);

        // ---- 3 gather-SpMV layers; acc deferred into the last ----
        const long long tthreads = (long long)N_NODES * 64;
        const int nblk = (int)((tthreads + 255) / 256);
        // L1: curb -> nxtb (e1)
        lgcn_spmv_mid<<<nblk, 256, 0, stream>>>(rowptr, csr, curb, nxtb);
        // L2: nxtb -> e2b (aliases cvp)
        lgcn_spmv_mid<<<nblk, 256, 0, stream>>>(rowptr, csr, nxtb, e2b);
        // L3: gather from e2b, combine with e0 (f32 inputs) + e1 + e2 -> out
        lgcn_spmv_last<<<nblk, 256, 0, stream>>>(rowptr, csr, e2b, nxtb,
                                                 user_emb, item_emb, out);
    } else {
        // ---- fallback: atomic path (f32) ----
        float* curF = (float*)d_ws;
        float* nxtF = curF + buf_elems;
        const int total = N_NODES * EMBED_DIM / 4;
        lgcn_init<<<(total + 255) / 256, 256, 0, stream>>>(user_emb, item_emb, curF, out);
        float* a = curF; float* b = nxtF;
        for (int layer = 0; layer < N_LAYERS; ++layer) {
            hipMemsetAsync(b, 0, buf_elems * sizeof(float), stream);
            long long tthr = (long long)N_EDGES * 64;
            lgcn_spmm_atomic<<<(unsigned)((tthr + 255) / 256), 256, 0, stream>>>(
                adj_row, adj_col, adj_val, a, b);
            float s = (layer == N_LAYERS - 1) ? (1.0f / (N_LAYERS + 1)) : 1.0f;
            lgcn_accum<<<(total + 255) / 256, 256, 0, stream>>>(b, out, s);
            float* t = a; a = b; b = t;
        }
    }
}

// Round 20
// 413.351 us; speedup vs baseline: 1.1476x; 1.1476x over previous
//
#include <hip/hip_runtime.h>

#define N_USERS 100000
#define N_ITEMS 50000
#define N_NODES 150000
#define EMBED_DIM 64
#define N_EDGES 4800000
#define N_LAYERS 3

// two-level row radix: coarse buckets of 512 rows
#define CB_SHIFT 9
#define CB_ROWS (1 << CB_SHIFT)                          // 512
#define NC ((N_NODES + CB_ROWS - 1) >> CB_SHIFT)         // 293

#define EPB 16384                                        // edges per block (hist/part)
#define NPB ((N_EDGES + EPB - 1) / EPB)                  // 293
#define INIT_BLOCKS ((N_NODES * EMBED_DIM / 4 + 255) / 256)   // 9375

// ---------- bf16 helpers (RNE) ----------
__device__ __forceinline__ unsigned short f2bf(float f) {
    unsigned u = __float_as_uint(f);
    u += 0x7fffu + ((u >> 16) & 1u);
    return (unsigned short)(u >> 16);
}
__device__ __forceinline__ float bf2f(unsigned short h) {
    return __uint_as_float((unsigned)h << 16);
}

// ---------- packed edge: (col << 14) | val_e4m10 ----------
__device__ __forceinline__ unsigned enc_val14(unsigned vbits) {
    unsigned r = vbits + 0x1000u;              // round at dropped-bits midpoint
    unsigned exp = (r >> 23) & 0xffu;
    if (exp < 112u) return 0u;                 // decodes as 2^-15 (<=3e-5 err)
    return ((exp - 112u) << 10) | ((r >> 13) & 0x3ffu);
}
// 3-op decode: (p<<18) kills col bits; >>5 lands exp4 at [23:26], m10 at [13:22].
__device__ __forceinline__ float dec_val14(unsigned p) {
    return __uint_as_float(((p << 18) >> 5) + 0x38000000u);
}

// ---------------- fused: per-block coarse histogram + init cur0=bf16(emb) ----
__global__ __launch_bounds__(256)
void k_hist_init(const int* __restrict__ row, int* __restrict__ blk_hist,
                 const float* __restrict__ user_emb,
                 const float* __restrict__ item_emb,
                 unsigned short* __restrict__ curb) {
    __shared__ int h[NC];
    int blk = blockIdx.x;
    if (blk < NPB) {
        for (int i = threadIdx.x; i < NC; i += 256) h[i] = 0;
        __syncthreads();
        int e0 = blk * EPB;
        int e1 = e0 + EPB; if (e1 > N_EDGES) e1 = N_EDGES;
        for (int e = e0 + threadIdx.x; e < e1; e += 256)
            atomicAdd(&h[row[e] >> CB_SHIFT], 1);
        __syncthreads();
        for (int i = threadIdx.x; i < NC; i += 256)
            blk_hist[blk * NC + i] = h[i];
    } else {
        int i = (blk - NPB) * 256 + threadIdx.x;
        const int total = N_NODES * EMBED_DIM / 4;
        if (i >= total) return;
        const int user_elems = N_USERS * EMBED_DIM / 4;
        float4 v;
        if (i < user_elems) v = ((const float4*)user_emb)[i];
        else                v = ((const float4*)item_emb)[i - user_elems];
        ushort4 o;
        o.x = f2bf(v.x); o.y = f2bf(v.y); o.z = f2bf(v.z); o.w = f2bf(v.w);
        ((ushort4*)curb)[i] = o;
    }
}

// ---------------- 2D scan: bucket bases + exact per-(block,bucket) offsets ----
__global__ __launch_bounds__(512)
void k_scan2d(const int* __restrict__ bh,
              int* __restrict__ cbase,
              int* __restrict__ boff) {
    __shared__ int part[512];
    int t = threadIdx.x;
    int total = 0;
    if (t < NC)
        for (int blk = 0; blk < NPB; ++blk) total += bh[blk * NC + t];
    part[t] = total;
    __syncthreads();
    for (int o = 1; o < 512; o <<= 1) {
        int v = (t >= o) ? part[t - o] : 0;
        __syncthreads();
        part[t] += v;
        __syncthreads();
    }
    int base = t ? part[t - 1] : 0;     // exclusive
    if (t < NC) {
        cbase[t] = base;
        int run = base;
        for (int blk = 0; blk < NPB; ++blk) {
            boff[blk * NC + t] = run;
            run += bh[blk * NC + t];
        }
    }
    if (t == 0) cbase[NC] = N_EDGES;
}

// ---------------- single-pass partition with precomputed offsets ----------
// partition edge: (col << 9) | row_local(9b), val f32 bits (int2)
__global__ __launch_bounds__(256)
void k_part_f(const int* __restrict__ row,
              const int* __restrict__ col,
              const int* __restrict__ valI,
              const int* __restrict__ boff,
              int2* __restrict__ edges) {
    __shared__ int off[NC];
    int blk = blockIdx.x;
    int e0 = blk * EPB;
    int e1 = e0 + EPB; if (e1 > N_EDGES) e1 = N_EDGES;
    for (int i = threadIdx.x; i < NC; i += 256)
        off[i] = boff[blk * NC + i];
    __syncthreads();
    for (int e = e0 + threadIdx.x; e < e1; e += 256) {
        int r = row[e];
        int cb = r >> CB_SHIFT;
        int p = atomicAdd(&off[cb], 1);
        edges[p] = make_int2((col[e] << CB_SHIFT) | (r & (CB_ROWS - 1)), valI[e]);
    }
}

// ---------------- fine counting sort -> packed 4B CSR + rowptr ------------
__global__ __launch_bounds__(512)
void k_sort_c(const int* __restrict__ cbase,
              const int2* __restrict__ edges,
              unsigned* __restrict__ csr,
              int* __restrict__ rowptr) {
    __shared__ int h[CB_ROWS];
    __shared__ int off[CB_ROWS];
    int b = blockIdx.x;
    int seg0 = cbase[b], seg1 = cbase[b + 1];
    h[threadIdx.x] = 0;
    __syncthreads();
    for (int e = seg0 + threadIdx.x; e < seg1; e += 512)
        atomicAdd(&h[edges[e].x & (CB_ROWS - 1)], 1);
    __syncthreads();
    for (int o = 1; o < CB_ROWS; o <<= 1) {
        int t = (threadIdx.x >= o) ? h[threadIdx.x - o] : 0;
        __syncthreads();
        h[threadIdx.x] += t;
        __syncthreads();
    }
    int row0 = b << CB_SHIFT;
    int nrows = N_NODES - row0; if (nrows > CB_ROWS) nrows = CB_ROWS;
    int excl = threadIdx.x ? h[threadIdx.x - 1] : 0;
    off[threadIdx.x] = excl;
    if (threadIdx.x < nrows) rowptr[row0 + threadIdx.x] = seg0 + excl;
    __syncthreads();
    for (int e = seg0 + threadIdx.x; e < seg1; e += 512) {
        int2 ee = edges[e];
        int rl = ee.x & (CB_ROWS - 1);
        int p = atomicAdd(&off[rl], 1);
        unsigned colv = (unsigned)(ee.x >> CB_SHIFT);
        csr[seg0 + p] = (colv << 14) | enc_val14((unsigned)ee.y);
    }
    if (b == NC - 1 && threadIdx.x == 0) rowptr[N_NODES] = N_EDGES;
}

// ---------------- gather core: 16-deep MLP dot over one row ----------------
__device__ __forceinline__ float spmv_row(const unsigned* __restrict__ cv,
                                          const unsigned short* __restrict__ x,
                                          int start, int end, int lane) {
    float a0 = 0.f, a1 = 0.f, a2 = 0.f, a3 = 0.f;
    float a4 = 0.f, a5 = 0.f, a6 = 0.f, a7 = 0.f;
    int j = start;
    for (; j + 16 <= end; j += 16) {
        unsigned p0 = cv[j + 0],  p1 = cv[j + 1],  p2 = cv[j + 2],  p3 = cv[j + 3];
        unsigned p4 = cv[j + 4],  p5 = cv[j + 5],  p6 = cv[j + 6],  p7 = cv[j + 7];
        unsigned p8 = cv[j + 8],  p9 = cv[j + 9],  pa = cv[j + 10], pb = cv[j + 11];
        unsigned pc = cv[j + 12], pd = cv[j + 13], pe = cv[j + 14], pf = cv[j + 15];
        float x0 = bf2f(x[((size_t)(p0 >> 14) << 6) + lane]);
        float x1 = bf2f(x[((size_t)(p1 >> 14) << 6) + lane]);
        float x2 = bf2f(x[((size_t)(p2 >> 14) << 6) + lane]);
        float x3 = bf2f(x[((size_t)(p3 >> 14) << 6) + lane]);
        float x4 = bf2f(x[((size_t)(p4 >> 14) << 6) + lane]);
        float x5 = bf2f(x[((size_t)(p5 >> 14) << 6) + lane]);
        float x6 = bf2f(x[((size_t)(p6 >> 14) << 6) + lane]);
        float x7 = bf2f(x[((size_t)(p7 >> 14) << 6) + lane]);
        float x8 = bf2f(x[((size_t)(p8 >> 14) << 6) + lane]);
        float x9 = bf2f(x[((size_t)(p9 >> 14) << 6) + lane]);
        float xa = bf2f(x[((size_t)(pa >> 14) << 6) + lane]);
        float xb = bf2f(x[((size_t)(pb >> 14) << 6) + lane]);
        float xc = bf2f(x[((size_t)(pc >> 14) << 6) + lane]);
        float xd = bf2f(x[((size_t)(pd >> 14) << 6) + lane]);
        float xe = bf2f(x[((size_t)(pe >> 14) << 6) + lane]);
        float xf = bf2f(x[((size_t)(pf >> 14) << 6) + lane]);
        a0 += dec_val14(p0) * x0;  a1 += dec_val14(p1) * x1;
        a2 += dec_val14(p2) * x2;  a3 += dec_val14(p3) * x3;
        a4 += dec_val14(p4) * x4;  a5 += dec_val14(p5) * x5;
        a6 += dec_val14(p6) * x6;  a7 += dec_val14(p7) * x7;
        a0 += dec_val14(p8) * x8;  a1 += dec_val14(p9) * x9;
        a2 += dec_val14(pa) * xa;  a3 += dec_val14(pb) * xb;
        a4 += dec_val14(pc) * xc;  a5 += dec_val14(pd) * xd;
        a6 += dec_val14(pe) * xe;  a7 += dec_val14(pf) * xf;
    }
    if (j + 8 <= end) {
        unsigned p0 = cv[j + 0], p1 = cv[j + 1], p2 = cv[j + 2], p3 = cv[j + 3];
        unsigned p4 = cv[j + 4], p5 = cv[j + 5], p6 = cv[j + 6], p7 = cv[j + 7];
        a0 += dec_val14(p0) * bf2f(x[((size_t)(p0 >> 14) << 6) + lane]);
        a1 += dec_val14(p1) * bf2f(x[((size_t)(p1 >> 14) << 6) + lane]);
        a2 += dec_val14(p2) * bf2f(x[((size_t)(p2 >> 14) << 6) + lane]);
        a3 += dec_val14(p3) * bf2f(x[((size_t)(p3 >> 14) << 6) + lane]);
        a4 += dec_val14(p4) * bf2f(x[((size_t)(p4 >> 14) << 6) + lane]);
        a5 += dec_val14(p5) * bf2f(x[((size_t)(p5 >> 14) << 6) + lane]);
        a6 += dec_val14(p6) * bf2f(x[((size_t)(p6 >> 14) << 6) + lane]);
        a7 += dec_val14(p7) * bf2f(x[((size_t)(p7 >> 14) << 6) + lane]);
        j += 8;
    }
    if (j + 4 <= end) {
        unsigned p0 = cv[j + 0], p1 = cv[j + 1], p2 = cv[j + 2], p3 = cv[j + 3];
        a0 += dec_val14(p0) * bf2f(x[((size_t)(p0 >> 14) << 6) + lane]);
        a1 += dec_val14(p1) * bf2f(x[((size_t)(p1 >> 14) << 6) + lane]);
        a2 += dec_val14(p2) * bf2f(x[((size_t)(p2 >> 14) << 6) + lane]);
        a3 += dec_val14(p3) * bf2f(x[((size_t)(p3 >> 14) << 6) + lane]);
        j += 4;
    }
    for (; j < end; ++j) {
        unsigned p = cv[j];
        a0 += dec_val14(p) * bf2f(x[((size_t)(p >> 14) << 6) + lane]);
    }
    return ((a0 + a1) + (a2 + a3)) + ((a4 + a5) + (a6 + a7));
}

// ---------------- layers 1..L-1: gather SpMV, write bf16 nxt only ----------------
__global__ __launch_bounds__(256)
void lgcn_spmv_mid(const int* __restrict__ rowptr,
                   const unsigned* __restrict__ cv,
                   const unsigned short* __restrict__ x,
                   unsigned short* __restrict__ nxt) {
    int t = blockIdx.x * blockDim.x + threadIdx.x;
    int wave = t >> 6;
    int lane = t & 63;
    if (wave >= N_NODES) return;
    int r = __builtin_amdgcn_readfirstlane(wave);
    float sum = spmv_row(cv, x, rowptr[r], rowptr[r + 1], lane);
    nxt[((size_t)r << 6) + lane] = f2bf(sum);
}

// ---------------- last layer: gather + fused final combine ----------------
__global__ __launch_bounds__(256)
void lgcn_spmv_last(const int* __restrict__ rowptr,
                    const unsigned* __restrict__ cv,
                    const unsigned short* __restrict__ x,     // e2 (bf16)
                    const unsigned short* __restrict__ e1,    // layer-1 out (bf16)
                    const float* __restrict__ user_emb,
                    const float* __restrict__ item_emb,
                    float* __restrict__ out) {
    int t = blockIdx.x * blockDim.x + threadIdx.x;
    int wave = t >> 6;
    int lane = t & 63;
    if (wave >= N_NODES) return;
    int r = __builtin_amdgcn_readfirstlane(wave);
    float sum = spmv_row(cv, x, rowptr[r], rowptr[r + 1], lane);
    size_t o = ((size_t)r << 6) + lane;
    float e0 = (r < N_USERS) ? user_emb[o]
                             : item_emb[o - ((size_t)N_USERS << 6)];
    float v = ((e0 + bf2f(e1[o])) + bf2f(x[o])) + sum;
    out[o] = v * 0.25f;
}

// ---------------- fallback (atomic scatter, f32) ----------------
__global__ void lgcn_init(const float* __restrict__ user_emb,
                          const float* __restrict__ item_emb,
                          float* __restrict__ cur,
                          float* __restrict__ acc) {
    int i = blockIdx.x * blockDim.x + threadIdx.x;
    const int total = N_NODES * EMBED_DIM / 4;
    if (i >= total) return;
    const int user_elems = N_USERS * EMBED_DIM / 4;
    float4 v;
    if (i < user_elems) v = ((const float4*)user_emb)[i];
    else                v = ((const float4*)item_emb)[i - user_elems];
    ((float4*)cur)[i] = v;
    ((float4*)acc)[i] = v;
}

__global__ void lgcn_spmm_atomic(const int* __restrict__ row,
                                 const int* __restrict__ col,
                                 const float* __restrict__ val,
                                 const float* __restrict__ x,
                                 float* __restrict__ y) {
    long long t = (long long)blockIdx.x * blockDim.x + threadIdx.x;
    int e = (int)(t >> 6);
    int d = (int)(t & 63);
    if (e >= N_EDGES) return;
    atomicAdd(&y[(long long)row[e] * EMBED_DIM + d],
              val[e] * x[(long long)col[e] * EMBED_DIM + d]);
}

__global__ void lgcn_accum(const float* __restrict__ cur,
                           float* __restrict__ acc, float s) {
    int i = blockIdx.x * blockDim.x + threadIdx.x;
    const int total = N_NODES * EMBED_DIM / 4;
    if (i >= total) return;
    float4 a = ((const float4*)acc)[i];
    float4 c = ((const float4*)cur)[i];
    a.x = (a.x + c.x) * s; a.y = (a.y + c.y) * s;
    a.z = (a.z + c.z) * s; a.w = (a.w + c.w) * s;
    ((float4*)acc)[i] = a;
}

extern "C" void kernel_launch(void* const* d_in, const int* in_sizes, int n_in,
                              void* d_out, int out_size, void* d_ws, size_t ws_size,
                              hipStream_t stream) {
    const int*   adj_row  = (const int*)d_in[0];
    const int*   adj_col  = (const int*)d_in[1];
    const float* adj_val  = (const float*)d_in[2];
    const int*   adj_valI = (const int*)d_in[2];
    const float* user_emb = (const float*)d_in[3];
    const float* item_emb = (const float*)d_in[4];
    float* out = (float*)d_out;

    const size_t buf_elems = (size_t)N_NODES * EMBED_DIM;

    // ---- workspace layout ----
    char* wp = (char*)d_ws;
    int* cbase  = (int*)wp;  wp += (size_t)(NC + 1) * sizeof(int);
    int* rowptr = (int*)wp;  wp += (size_t)(N_NODES + 1) * sizeof(int);
    wp = (char*)(((size_t)wp + 127) & ~(size_t)127);
    int2* edges  = (int2*)wp; wp += (size_t)N_EDGES * sizeof(int2);
    wp = (char*)(((size_t)wp + 127) & ~(size_t)127);
    unsigned* csr = (unsigned*)wp; wp += (size_t)N_EDGES * sizeof(unsigned);
    wp = (char*)(((size_t)wp + 127) & ~(size_t)127);
    unsigned short* curb = (unsigned short*)wp; wp += buf_elems * sizeof(unsigned short);
    wp = (char*)(((size_t)wp + 127) & ~(size_t)127);
    unsigned short* nxtb = (unsigned short*)wp; wp += buf_elems * sizeof(unsigned short);
    size_t needed = (size_t)(wp - (char*)d_ws);
    // blk_hist/boff alias the csr region (dead until k_sort_c writes it);
    // e2 buffer aliases the edges region (dead after k_sort_c).
    int* blk_hist = (int*)csr;                       // NPB*NC ints (~343 KB)
    int* boff     = blk_hist + (size_t)NPB * NC;     // NPB*NC ints
    unsigned short* e2b = (unsigned short*)edges;

    if (needed <= ws_size) {
        // ---- build: fused per-block hist + init, 2D scan, offset-scatter, sort ----
        k_hist_init<<<NPB + INIT_BLOCKS, 256, 0, stream>>>(adj_row, blk_hist,
                                                           user_emb, item_emb, curb);
        k_scan2d<<<1, 512, 0, stream>>>(blk_hist, cbase, boff);
        k_part_f<<<NPB, 256, 0, stream>>>(adj_row, adj_col, adj_valI, boff, edges);
        k_sort_c<<<NC, 512, 0, stream>>>(cbase, edges, csr, rowptr);

        // ---- 3 gather-SpMV layers; acc deferred into the last ----
        const long long tthreads = (long long)N_NODES * 64;
        const int nblk = (int)((tthreads + 255) / 256);
        // L1: curb -> nxtb (e1)
        lgcn_spmv_mid<<<nblk, 256, 0, stream>>>(rowptr, csr, curb, nxtb);
        // L2: nxtb -> e2b (aliases edges)
        lgcn_spmv_mid<<<nblk, 256, 0, stream>>>(rowptr, csr, nxtb, e2b);
        // L3: gather from e2b, combine with e0 (f32 inputs) + e1 + e2 -> out
        lgcn_spmv_last<<<nblk, 256, 0, stream>>>(rowptr, csr, e2b, nxtb,
                                                 user_emb, item_emb, out);
    } else {
        // ---- fallback: atomic path (f32) ----
        float* curF = (float*)d_ws;
        float* nxtF = curF + buf_elems;
        const int total = N_NODES * EMBED_DIM / 4;
        lgcn_init<<<(total + 255) / 256, 256, 0, stream>>>(user_emb, item_emb, curF, out);
        float* a = curF; float* b = nxtF;
        for (int layer = 0; layer < N_LAYERS; ++layer) {
            hipMemsetAsync(b, 0, buf_elems * sizeof(float), stream);
            long long tthr = (long long)N_EDGES * 64;
            lgcn_spmm_atomic<<<(unsigned)((tthr + 255) / 256), 256, 0, stream>>>(
                adj_row, adj_col, adj_val, a, b);
            float s = (layer == N_LAYERS - 1) ? (1.0f / (N_LAYERS + 1)) : 1.0f;
            lgcn_accum<<<(total + 255) / 256, 256, 0, stream>>>(b, out, s);
            float* t = a; a = b; b = t;
        }
    }
}

// Round 21
// 408.763 us; speedup vs baseline: 1.1605x; 1.0112x over previous
//
#include <hip/hip_runtime.h>

#define N_USERS 100000
#define N_ITEMS 50000
#define N_NODES 150000
#define EMBED_DIM 64
#define N_EDGES 4800000
#define N_LAYERS 3

// two-level row radix: coarse buckets of 512 rows
#define CB_SHIFT 9
#define CB_ROWS (1 << CB_SHIFT)                          // 512
#define NC ((N_NODES + CB_ROWS - 1) >> CB_SHIFT)         // 293

#define EPB 16384                                        // edges per block (hist/part)
#define NPB ((N_EDGES + EPB - 1) / EPB)                  // 293
#define INIT_BLOCKS ((N_NODES * EMBED_DIM / 4 + 255) / 256)   // 9375

// ---------- bf16 helpers (RNE) ----------
__device__ __forceinline__ unsigned short f2bf(float f) {
    unsigned u = __float_as_uint(f);
    u += 0x7fffu + ((u >> 16) & 1u);
    return (unsigned short)(u >> 16);
}
__device__ __forceinline__ float bf2f(unsigned short h) {
    return __uint_as_float((unsigned)h << 16);
}

// ---------- packed edge: (col << 14) | val_e4m10 ----------
__device__ __forceinline__ unsigned enc_val14(unsigned vbits) {
    unsigned r = vbits + 0x1000u;              // round at dropped-bits midpoint
    unsigned exp = (r >> 23) & 0xffu;
    if (exp < 112u) return 0u;                 // decodes as 2^-15 (<=3e-5 err)
    return ((exp - 112u) << 10) | ((r >> 13) & 0x3ffu);
}
// 3-op decode: (p<<18) kills col bits; >>5 lands exp4 at [23:26], m10 at [13:22].
__device__ __forceinline__ float dec_val14(unsigned p) {
    return __uint_as_float(((p << 18) >> 5) + 0x38000000u);
}

// ---------------- fused: per-block coarse histogram + init cur0=bf16(emb) ----
__global__ __launch_bounds__(256)
void k_hist_init(const int* __restrict__ row, int* __restrict__ blk_hist,
                 const float* __restrict__ user_emb,
                 const float* __restrict__ item_emb,
                 unsigned short* __restrict__ curb) {
    __shared__ int h[NC];
    int blk = blockIdx.x;
    if (blk < NPB) {
        for (int i = threadIdx.x; i < NC; i += 256) h[i] = 0;
        __syncthreads();
        int e0 = blk * EPB;
        int e1 = e0 + EPB; if (e1 > N_EDGES) e1 = N_EDGES;
        for (int e = e0 + threadIdx.x; e < e1; e += 256)
            atomicAdd(&h[row[e] >> CB_SHIFT], 1);
        __syncthreads();
        for (int i = threadIdx.x; i < NC; i += 256)
            blk_hist[blk * NC + i] = h[i];
    } else {
        int i = (blk - NPB) * 256 + threadIdx.x;
        const int total = N_NODES * EMBED_DIM / 4;
        if (i >= total) return;
        const int user_elems = N_USERS * EMBED_DIM / 4;
        float4 v;
        if (i < user_elems) v = ((const float4*)user_emb)[i];
        else                v = ((const float4*)item_emb)[i - user_elems];
        ushort4 o;
        o.x = f2bf(v.x); o.y = f2bf(v.y); o.z = f2bf(v.z); o.w = f2bf(v.w);
        ((ushort4*)curb)[i] = o;
    }
}

// ---------------- 2D scan: bucket bases + exact per-(block,bucket) offsets ----
__global__ __launch_bounds__(512)
void k_scan2d(const int* __restrict__ bh,
              int* __restrict__ cbase,
              int* __restrict__ boff) {
    __shared__ int part[512];
    int t = threadIdx.x;
    int total = 0;
    if (t < NC)
        for (int blk = 0; blk < NPB; ++blk) total += bh[blk * NC + t];
    part[t] = total;
    __syncthreads();
    for (int o = 1; o < 512; o <<= 1) {
        int v = (t >= o) ? part[t - o] : 0;
        __syncthreads();
        part[t] += v;
        __syncthreads();
    }
    int base = t ? part[t - 1] : 0;     // exclusive
    if (t < NC) {
        cbase[t] = base;
        int run = base;
        for (int blk = 0; blk < NPB; ++blk) {
            boff[blk * NC + t] = run;
            run += bh[blk * NC + t];
        }
    }
    if (t == 0) cbase[NC] = N_EDGES;
}

// ---------------- single-pass partition with precomputed offsets ----------
// partition edge: (col << 9) | row_local(9b), val f32 bits (int2)
// 1024 threads: the scatter is parallelism-starved at 256 (r20: 10.9% occ).
__global__ __launch_bounds__(1024)
void k_part_f(const int* __restrict__ row,
              const int* __restrict__ col,
              const int* __restrict__ valI,
              const int* __restrict__ boff,
              int2* __restrict__ edges) {
    __shared__ int off[NC];
    int blk = blockIdx.x;
    int e0 = blk * EPB;
    int e1 = e0 + EPB; if (e1 > N_EDGES) e1 = N_EDGES;
    for (int i = threadIdx.x; i < NC; i += 1024)
        off[i] = boff[blk * NC + i];
    __syncthreads();
    for (int e = e0 + threadIdx.x; e < e1; e += 1024) {
        int r = row[e];
        int cb = r >> CB_SHIFT;
        int p = atomicAdd(&off[cb], 1);
        edges[p] = make_int2((col[e] << CB_SHIFT) | (r & (CB_ROWS - 1)), valI[e]);
    }
}

// ---------------- fine counting sort -> packed 4B CSR + rowptr ------------
__global__ __launch_bounds__(512)
void k_sort_c(const int* __restrict__ cbase,
              const int2* __restrict__ edges,
              unsigned* __restrict__ csr,
              int* __restrict__ rowptr) {
    __shared__ int h[CB_ROWS];
    __shared__ int off[CB_ROWS];
    int b = blockIdx.x;
    int seg0 = cbase[b], seg1 = cbase[b + 1];
    h[threadIdx.x] = 0;
    __syncthreads();
    for (int e = seg0 + threadIdx.x; e < seg1; e += 512)
        atomicAdd(&h[edges[e].x & (CB_ROWS - 1)], 1);
    __syncthreads();
    for (int o = 1; o < CB_ROWS; o <<= 1) {
        int t = (threadIdx.x >= o) ? h[threadIdx.x - o] : 0;
        __syncthreads();
        h[threadIdx.x] += t;
        __syncthreads();
    }
    int row0 = b << CB_SHIFT;
    int nrows = N_NODES - row0; if (nrows > CB_ROWS) nrows = CB_ROWS;
    int excl = threadIdx.x ? h[threadIdx.x - 1] : 0;
    off[threadIdx.x] = excl;
    if (threadIdx.x < nrows) rowptr[row0 + threadIdx.x] = seg0 + excl;
    __syncthreads();
    for (int e = seg0 + threadIdx.x; e < seg1; e += 512) {
        int2 ee = edges[e];
        int rl = ee.x & (CB_ROWS - 1);
        int p = atomicAdd(&off[rl], 1);
        unsigned colv = (unsigned)(ee.x >> CB_SHIFT);
        csr[seg0 + p] = (colv << 14) | enc_val14((unsigned)ee.y);
    }
    if (b == NC - 1 && threadIdx.x == 0) rowptr[N_NODES] = N_EDGES;
}

// ---------------- gather core: 16-deep MLP dot over one row ----------------
__device__ __forceinline__ float spmv_row(const unsigned* __restrict__ cv,
                                          const unsigned short* __restrict__ x,
                                          int start, int end, int lane) {
    float a0 = 0.f, a1 = 0.f, a2 = 0.f, a3 = 0.f;
    float a4 = 0.f, a5 = 0.f, a6 = 0.f, a7 = 0.f;
    int j = start;
    for (; j + 16 <= end; j += 16) {
        unsigned p0 = cv[j + 0],  p1 = cv[j + 1],  p2 = cv[j + 2],  p3 = cv[j + 3];
        unsigned p4 = cv[j + 4],  p5 = cv[j + 5],  p6 = cv[j + 6],  p7 = cv[j + 7];
        unsigned p8 = cv[j + 8],  p9 = cv[j + 9],  pa = cv[j + 10], pb = cv[j + 11];
        unsigned pc = cv[j + 12], pd = cv[j + 13], pe = cv[j + 14], pf = cv[j + 15];
        float x0 = bf2f(x[((size_t)(p0 >> 14) << 6) + lane]);
        float x1 = bf2f(x[((size_t)(p1 >> 14) << 6) + lane]);
        float x2 = bf2f(x[((size_t)(p2 >> 14) << 6) + lane]);
        float x3 = bf2f(x[((size_t)(p3 >> 14) << 6) + lane]);
        float x4 = bf2f(x[((size_t)(p4 >> 14) << 6) + lane]);
        float x5 = bf2f(x[((size_t)(p5 >> 14) << 6) + lane]);
        float x6 = bf2f(x[((size_t)(p6 >> 14) << 6) + lane]);
        float x7 = bf2f(x[((size_t)(p7 >> 14) << 6) + lane]);
        float x8 = bf2f(x[((size_t)(p8 >> 14) << 6) + lane]);
        float x9 = bf2f(x[((size_t)(p9 >> 14) << 6) + lane]);
        float xa = bf2f(x[((size_t)(pa >> 14) << 6) + lane]);
        float xb = bf2f(x[((size_t)(pb >> 14) << 6) + lane]);
        float xc = bf2f(x[((size_t)(pc >> 14) << 6) + lane]);
        float xd = bf2f(x[((size_t)(pd >> 14) << 6) + lane]);
        float xe = bf2f(x[((size_t)(pe >> 14) << 6) + lane]);
        float xf = bf2f(x[((size_t)(pf >> 14) << 6) + lane]);
        a0 += dec_val14(p0) * x0;  a1 += dec_val14(p1) * x1;
        a2 += dec_val14(p2) * x2;  a3 += dec_val14(p3) * x3;
        a4 += dec_val14(p4) * x4;  a5 += dec_val14(p5) * x5;
        a6 += dec_val14(p6) * x6;  a7 += dec_val14(p7) * x7;
        a0 += dec_val14(p8) * x8;  a1 += dec_val14(p9) * x9;
        a2 += dec_val14(pa) * xa;  a3 += dec_val14(pb) * xb;
        a4 += dec_val14(pc) * xc;  a5 += dec_val14(pd) * xd;
        a6 += dec_val14(pe) * xe;  a7 += dec_val14(pf) * xf;
    }
    if (j + 8 <= end) {
        unsigned p0 = cv[j + 0], p1 = cv[j + 1], p2 = cv[j + 2], p3 = cv[j + 3];
        unsigned p4 = cv[j + 4], p5 = cv[j + 5], p6 = cv[j + 6], p7 = cv[j + 7];
        a0 += dec_val14(p0) * bf2f(x[((size_t)(p0 >> 14) << 6) + lane]);
        a1 += dec_val14(p1) * bf2f(x[((size_t)(p1 >> 14) << 6) + lane]);
        a2 += dec_val14(p2) * bf2f(x[((size_t)(p2 >> 14) << 6) + lane]);
        a3 += dec_val14(p3) * bf2f(x[((size_t)(p3 >> 14) << 6) + lane]);
        a4 += dec_val14(p4) * bf2f(x[((size_t)(p4 >> 14) << 6) + lane]);
        a5 += dec_val14(p5) * bf2f(x[((size_t)(p5 >> 14) << 6) + lane]);
        a6 += dec_val14(p6) * bf2f(x[((size_t)(p6 >> 14) << 6) + lane]);
        a7 += dec_val14(p7) * bf2f(x[((size_t)(p7 >> 14) << 6) + lane]);
        j += 8;
    }
    if (j + 4 <= end) {
        unsigned p0 = cv[j + 0], p1 = cv[j + 1], p2 = cv[j + 2], p3 = cv[j + 3];
        a0 += dec_val14(p0) * bf2f(x[((size_t)(p0 >> 14) << 6) + lane]);
        a1 += dec_val14(p1) * bf2f(x[((size_t)(p1 >> 14) << 6) + lane]);
        a2 += dec_val14(p2) * bf2f(x[((size_t)(p2 >> 14) << 6) + lane]);
        a3 += dec_val14(p3) * bf2f(x[((size_t)(p3 >> 14) << 6) + lane]);
        j += 4;
    }
    for (; j < end; ++j) {
        unsigned p = cv[j];
        a0 += dec_val14(p) * bf2f(x[((size_t)(p >> 14) << 6) + lane]);
    }
    return ((a0 + a1) + (a2 + a3)) + ((a4 + a5) + (a6 + a7));
}

// ---------------- layers 1..L-1: gather SpMV, write bf16 nxt only ----------------
__global__ __launch_bounds__(256)
void lgcn_spmv_mid(const int* __restrict__ rowptr,
                   const unsigned* __restrict__ cv,
                   const unsigned short* __restrict__ x,
                   unsigned short* __restrict__ nxt) {
    int t = blockIdx.x * blockDim.x + threadIdx.x;
    int wave = t >> 6;
    int lane = t & 63;
    if (wave >= N_NODES) return;
    int r = __builtin_amdgcn_readfirstlane(wave);
    float sum = spmv_row(cv, x, rowptr[r], rowptr[r + 1], lane);
    nxt[((size_t)r << 6) + lane] = f2bf(sum);
}

// ---------------- last layer: gather + fused final combine ----------------
__global__ __launch_bounds__(256)
void lgcn_spmv_last(const int* __restrict__ rowptr,
                    const unsigned* __restrict__ cv,
                    const unsigned short* __restrict__ x,     // e2 (bf16)
                    const unsigned short* __restrict__ e1,    // layer-1 out (bf16)
                    const float* __restrict__ user_emb,
                    const float* __restrict__ item_emb,
                    float* __restrict__ out) {
    int t = blockIdx.x * blockDim.x + threadIdx.x;
    int wave = t >> 6;
    int lane = t & 63;
    if (wave >= N_NODES) return;
    int r = __builtin_amdgcn_readfirstlane(wave);
    float sum = spmv_row(cv, x, rowptr[r], rowptr[r + 1], lane);
    size_t o = ((size_t)r << 6) + lane;
    float e0 = (r < N_USERS) ? user_emb[o]
                             : item_emb[o - ((size_t)N_USERS << 6)];
    float v = ((e0 + bf2f(e1[o])) + bf2f(x[o])) + sum;
    out[o] = v * 0.25f;
}

// ---------------- fallback (atomic scatter, f32) ----------------
__global__ void lgcn_init(const float* __restrict__ user_emb,
                          const float* __restrict__ item_emb,
                          float* __restrict__ cur,
                          float* __restrict__ acc) {
    int i = blockIdx.x * blockDim.x + threadIdx.x;
    const int total = N_NODES * EMBED_DIM / 4;
    if (i >= total) return;
    const int user_elems = N_USERS * EMBED_DIM / 4;
    float4 v;
    if (i < user_elems) v = ((const float4*)user_emb)[i];
    else                v = ((const float4*)item_emb)[i - user_elems];
    ((float4*)cur)[i] = v;
    ((float4*)acc)[i] = v;
}

__global__ void lgcn_spmm_atomic(const int* __restrict__ row,
                                 const int* __restrict__ col,
                                 const float* __restrict__ val,
                                 const float* __restrict__ x,
                                 float* __restrict__ y) {
    long long t = (long long)blockIdx.x * blockDim.x + threadIdx.x;
    int e = (int)(t >> 6);
    int d = (int)(t & 63);
    if (e >= N_EDGES) return;
    atomicAdd(&y[(long long)row[e] * EMBED_DIM + d],
              val[e] * x[(long long)col[e] * EMBED_DIM + d]);
}

__global__ void lgcn_accum(const float* __restrict__ cur,
                           float* __restrict__ acc, float s) {
    int i = blockIdx.x * blockDim.x + threadIdx.x;
    const int total = N_NODES * EMBED_DIM / 4;
    if (i >= total) return;
    float4 a = ((const float4*)acc)[i];
    float4 c = ((const float4*)cur)[i];
    a.x = (a.x + c.x) * s; a.y = (a.y + c.y) * s;
    a.z = (a.z + c.z) * s; a.w = (a.w + c.w) * s;
    ((float4*)acc)[i] = a;
}

extern "C" void kernel_launch(void* const* d_in, const int* in_sizes, int n_in,
                              void* d_out, int out_size, void* d_ws, size_t ws_size,
                              hipStream_t stream) {
    const int*   adj_row  = (const int*)d_in[0];
    const int*   adj_col  = (const int*)d_in[1];
    const float* adj_val  = (const float*)d_in[2];
    const int*   adj_valI = (const int*)d_in[2];
    const float* user_emb = (const float*)d_in[3];
    const float* item_emb = (const float*)d_in[4];
    float* out = (float*)d_out;

    const size_t buf_elems = (size_t)N_NODES * EMBED_DIM;

    // ---- workspace layout ----
    char* wp = (char*)d_ws;
    int* cbase  = (int*)wp;  wp += (size_t)(NC + 1) * sizeof(int);
    int* rowptr = (int*)wp;  wp += (size_t)(N_NODES + 1) * sizeof(int);
    wp = (char*)(((size_t)wp + 127) & ~(size_t)127);
    int2* edges  = (int2*)wp; wp += (size_t)N_EDGES * sizeof(int2);
    wp = (char*)(((size_t)wp + 127) & ~(size_t)127);
    unsigned* csr = (unsigned*)wp; wp += (size_t)N_EDGES * sizeof(unsigned);
    wp = (char*)(((size_t)wp + 127) & ~(size_t)127);
    unsigned short* curb = (unsigned short*)wp; wp += buf_elems * sizeof(unsigned short);
    wp = (char*)(((size_t)wp + 127) & ~(size_t)127);
    unsigned short* nxtb = (unsigned short*)wp; wp += buf_elems * sizeof(unsigned short);
    size_t needed = (size_t)(wp - (char*)d_ws);
    // blk_hist/boff alias the csr region (dead until k_sort_c writes it);
    // e2 buffer aliases the edges region (dead after k_sort_c).
    int* blk_hist = (int*)csr;                       // NPB*NC ints (~343 KB)
    int* boff     = blk_hist + (size_t)NPB * NC;     // NPB*NC ints
    unsigned short* e2b = (unsigned short*)edges;

    if (needed <= ws_size) {
        // ---- build: fused per-block hist + init, 2D scan, offset-scatter, sort ----
        k_hist_init<<<NPB + INIT_BLOCKS, 256, 0, stream>>>(adj_row, blk_hist,
                                                           user_emb, item_emb, curb);
        k_scan2d<<<1, 512, 0, stream>>>(blk_hist, cbase, boff);
        k_part_f<<<NPB, 1024, 0, stream>>>(adj_row, adj_col, adj_valI, boff, edges);
        k_sort_c<<<NC, 512, 0, stream>>>(cbase, edges, csr, rowptr);

        // ---- 3 gather-SpMV layers; acc deferred into the last ----
        const long long tthreads = (long long)N_NODES * 64;
        const int nblk = (int)((tthreads + 255) / 256);
        // L1: curb -> nxtb (e1)
        lgcn_spmv_mid<<<nblk, 256, 0, stream>>>(rowptr, csr, curb, nxtb);
        // L2: nxtb -> e2b (aliases edges)
        lgcn_spmv_mid<<<nblk, 256, 0, stream>>>(rowptr, csr, nxtb, e2b);
        // L3: gather from e2b, combine with e0 (f32 inputs) + e1 + e2 -> out
        lgcn_spmv_last<<<nblk, 256, 0, stream>>>(rowptr, csr, e2b, nxtb,
                                                 user_emb, item_emb, out);
    } else {
        // ---- fallback: atomic path (f32) ----
        float* curF = (float*)d_ws;
        float* nxtF = curF + buf_elems;
        const int total = N_NODES * EMBED_DIM / 4;
        lgcn_init<<<(total + 255) / 256, 256, 0, stream>>>(user_emb, item_emb, curF, out);
        float* a = curF; float* b = nxtF;
        for (int layer = 0; layer < N_LAYERS; ++layer) {
            hipMemsetAsync(b, 0, buf_elems * sizeof(float), stream);
            long long tthr = (long long)N_EDGES * 64;
            lgcn_spmm_atomic<<<(unsigned)((tthr + 255) / 256), 256, 0, stream>>>(
                adj_row, adj_col, adj_val, a, b);
            float s = (layer == N_LAYERS - 1) ? (1.0f / (N_LAYERS + 1)) : 1.0f;
            lgcn_accum<<<(total + 255) / 256, 256, 0, stream>>>(b, out, s);
            float* t = a; a = b; b = t;
        }
    }
}